// Round 2
// baseline (1640.771 us; speedup 1.0000x reference)
//
#include <hip/hip_runtime.h>
#include <hip/hip_bf16.h>
#include <math.h>

#define Bdim 2
#define Tdim 2048
#define Cdim 1024
#define Hdim 16
#define Dh 64
#define SCALE 0.125f
#define M_TOT (Bdim * Tdim)  // 4096

// ---------------------------------------------------------------------------
// Column mean over T: m[b][c] = (1/T) sum_t x[b,t,c].  grid (B, C/256, 8)
// ---------------------------------------------------------------------------
__global__ void colmean_kernel(const float* __restrict__ x, float* __restrict__ m) {
    int b = blockIdx.x;
    int c = blockIdx.y * 256 + threadIdx.x;
    int t0 = blockIdx.z * 256;
    float s = 0.f;
    for (int t = t0; t < t0 + 256; ++t)
        s += x[((size_t)b * Tdim + t) * Cdim + c];
    atomicAdd(&m[b * Cdim + c], s * (1.0f / Tdim));
}

// ---------------------------------------------------------------------------
// out[r][c] = sum_k rows[r][k] * W[k][c] + bias[c].   grid (C/256, R)
// ---------------------------------------------------------------------------
__global__ void gemv3_kernel(const float* __restrict__ rows, const float* __restrict__ W,
                             const float* __restrict__ bias, float* __restrict__ out) {
    int c = blockIdx.x * 256 + threadIdx.x;
    int r = blockIdx.y;
    const float* rp = rows + (size_t)r * Cdim;
    float s = 0.f;
    for (int k = 0; k < Cdim; ++k)
        s += rp[k] * W[(size_t)k * Cdim + c];
    out[(size_t)r * Cdim + c] = s + bias[c];
}

__global__ void copyvec_kernel(const float* __restrict__ src, float* __restrict__ dst) {
    int i = blockIdx.x * 256 + threadIdx.x;
    dst[i] = src[i];
}

// ---------------------------------------------------------------------------
// Tiled fp32 GEMM: Cout[M,N] = A[M,K] @ W[K,N] + bias  (+epilogue)
// MODE 0: bias    MODE 1: tanh(bias+acc)    MODE 2: routing combine -> d_out
// BM=BN=64, BK=16, 256 threads (16x16), 4x4 microtile.
// ---------------------------------------------------------------------------
template <int MODE>
__global__ __launch_bounds__(256) void gemm_f32(
    const float* __restrict__ A, const float* __restrict__ W,
    const float* __restrict__ bias, float* __restrict__ Cout,
    int M, int N, int K,
    const float* __restrict__ routing, const float* __restrict__ cvec) {
    __shared__ float As[16][68];  // transposed: As[k][m], pad to 68 (16B-aligned rows)
    __shared__ float Ws[16][64];  // Ws[k][n]

    int tid = threadIdx.x;
    int tx = tid & 15, ty = tid >> 4;
    int m0 = blockIdx.y * 64, n0 = blockIdx.x * 64;

    float acc[4][4] = {};

    const float* Ablk = A + (size_t)m0 * K;
    const float* Wblk = W + n0;
    int lr = tid >> 2;         // 0..63 : row in A tile
    int lc = (tid & 3) * 4;    // 0,4,8,12 : k-col in A tile
    int wr = tid >> 4;         // 0..15 : k-row in W tile
    int wc = (tid & 15) * 4;   // col in W tile

    for (int k0 = 0; k0 < K; k0 += 16) {
        float4 av = *(const float4*)(Ablk + (size_t)lr * K + k0 + lc);
        float4 wv = *(const float4*)(Wblk + (size_t)(k0 + wr) * N + wc);
        __syncthreads();  // previous iteration finished reading LDS
        As[lc + 0][lr] = av.x;
        As[lc + 1][lr] = av.y;
        As[lc + 2][lr] = av.z;
        As[lc + 3][lr] = av.w;
        *(float4*)&Ws[wr][wc] = wv;
        __syncthreads();
#pragma unroll
        for (int kk = 0; kk < 16; ++kk) {
            float4 a4 = *(const float4*)&As[kk][ty * 4];
            float4 b4 = *(const float4*)&Ws[kk][tx * 4];
            float aa[4] = {a4.x, a4.y, a4.z, a4.w};
            float bb[4] = {b4.x, b4.y, b4.z, b4.w};
#pragma unroll
            for (int i = 0; i < 4; ++i)
#pragma unroll
                for (int j = 0; j < 4; ++j)
                    acc[i][j] += aa[i] * bb[j];
        }
    }

#pragma unroll
    for (int i = 0; i < 4; ++i) {
        int r = m0 + ty * 4 + i;
        float v[4];
#pragma unroll
        for (int j = 0; j < 4; ++j) {
            int c = n0 + tx * 4 + j;
            float t = acc[i][j] + bias[c];
            if (MODE == 1) t = tanhf(t);
            if (MODE == 2) {
                int b = r / Tdim;
                float r0 = routing[r * 3 + 0];
                float r1 = routing[r * 3 + 1];
                float r2 = routing[r * 3 + 2];
                t = r0 * t + r1 * cvec[b * Cdim + c] + r2 * cvec[2 * Cdim + c];
            }
            v[j] = t;
        }
        float4 v4 = {v[0], v[1], v[2], v[3]};
        *(float4*)(Cout + (size_t)r * N + n0 + tx * 4) = v4;
    }
}

// ---------------------------------------------------------------------------
// Routing: logits = R1 @ Wr2 + br2 (Wr2 is [C,3]); softmax over 3.
// One wave per (b,t) row; block = 4 waves. grid = M_TOT/4
// ---------------------------------------------------------------------------
__global__ __launch_bounds__(256) void routing_kernel(
    const float* __restrict__ R1, const float* __restrict__ Wr2,
    const float* __restrict__ br2, float* __restrict__ routing) {
    int wid = threadIdx.x >> 6, lane = threadIdx.x & 63;
    int row = blockIdx.x * 4 + wid;
    const float* rp = R1 + (size_t)row * Cdim;
    float a0 = 0.f, a1 = 0.f, a2 = 0.f;
    for (int k = lane; k < Cdim; k += 64) {
        float xv = rp[k];
        a0 += xv * Wr2[k * 3 + 0];
        a1 += xv * Wr2[k * 3 + 1];
        a2 += xv * Wr2[k * 3 + 2];
    }
#pragma unroll
    for (int off = 32; off; off >>= 1) {
        a0 += __shfl_xor(a0, off);
        a1 += __shfl_xor(a1, off);
        a2 += __shfl_xor(a2, off);
    }
    if (lane == 0) {
        a0 += br2[0]; a1 += br2[1]; a2 += br2[2];
        float mx = fmaxf(a0, fmaxf(a1, a2));
        float e0 = __expf(a0 - mx), e1 = __expf(a1 - mx), e2 = __expf(a2 - mx);
        float inv = 1.0f / (e0 + e1 + e2);
        routing[row * 3 + 0] = e0 * inv;
        routing[row * 3 + 1] = e1 * inv;
        routing[row * 3 + 2] = e2 * inv;
    }
}

// ---------------------------------------------------------------------------
// Flash attention fp32 (level-1 only). grid (B*H, T/64), block 256.
// Q/K/V layout: [B,T,C] with head h at cols h*64..h*64+63.
// ---------------------------------------------------------------------------
__global__ __launch_bounds__(256) void flash_f32(
    const float* __restrict__ Qg, const float* __restrict__ Kg,
    const float* __restrict__ Vg, float* __restrict__ MO) {
    __shared__ float Qs[64][68];
    __shared__ float Ks[64][68];
    __shared__ float Vs[64][68];
    __shared__ float Ps[64][68];

    int bh = blockIdx.x;
    int b = bh >> 4, h = bh & 15;
    int qt = blockIdx.y;
    int tid = threadIdx.x;
    int tx = tid & 15, ty = tid >> 4;

    const size_t baseQ = ((size_t)(b * Tdim + qt * 64)) * Cdim + h * 64;
#pragma unroll
    for (int it = 0; it < 4; ++it) {
        int r = ty + it * 16;
        *(float4*)&Qs[r][tx * 4] = *(const float4*)(Qg + baseQ + (size_t)r * Cdim + tx * 4);
    }

    float m_run[4], l_run[4], O[4][4];
#pragma unroll
    for (int i = 0; i < 4; ++i) {
        m_run[i] = -1e30f;
        l_run[i] = 0.f;
#pragma unroll
        for (int j = 0; j < 4; ++j) O[i][j] = 0.f;
    }

    for (int kt = 0; kt < Tdim / 64; ++kt) {
        const size_t baseK = ((size_t)(b * Tdim + kt * 64)) * Cdim + h * 64;
        float4 kreg[4], vreg[4];
#pragma unroll
        for (int it = 0; it < 4; ++it) {
            int r = ty + it * 16;
            kreg[it] = *(const float4*)(Kg + baseK + (size_t)r * Cdim + tx * 4);
            vreg[it] = *(const float4*)(Vg + baseK + (size_t)r * Cdim + tx * 4);
        }
        __syncthreads();  // everyone done reading Ks/Vs/Ps of previous tile
#pragma unroll
        for (int it = 0; it < 4; ++it) {
            int r = ty + it * 16;
            *(float4*)&Ks[r][tx * 4] = kreg[it];
            *(float4*)&Vs[r][tx * 4] = vreg[it];
        }
        __syncthreads();

        // S = Q K^T * SCALE  (4x4 per thread)
        float s[4][4] = {};
#pragma unroll
        for (int k4 = 0; k4 < 64; k4 += 4) {
            float4 qa[4], kb[4];
#pragma unroll
            for (int i = 0; i < 4; ++i) qa[i] = *(const float4*)&Qs[ty * 4 + i][k4];
#pragma unroll
            for (int j = 0; j < 4; ++j) kb[j] = *(const float4*)&Ks[tx * 4 + j][k4];
#pragma unroll
            for (int i = 0; i < 4; ++i)
#pragma unroll
                for (int j = 0; j < 4; ++j)
                    s[i][j] += qa[i].x * kb[j].x + qa[i].y * kb[j].y +
                               qa[i].z * kb[j].z + qa[i].w * kb[j].w;
        }

        // online softmax update
        float pl[4][4];
#pragma unroll
        for (int i = 0; i < 4; ++i) {
#pragma unroll
            for (int j = 0; j < 4; ++j) s[i][j] *= SCALE;
            float mx = fmaxf(fmaxf(s[i][0], s[i][1]), fmaxf(s[i][2], s[i][3]));
#pragma unroll
            for (int off = 1; off < 16; off <<= 1) mx = fmaxf(mx, __shfl_xor(mx, off, 16));
            float mnew = fmaxf(m_run[i], mx);
            float corr = __expf(m_run[i] - mnew);
            float psum = 0.f;
#pragma unroll
            for (int j = 0; j < 4; ++j) {
                pl[i][j] = __expf(s[i][j] - mnew);
                psum += pl[i][j];
            }
#pragma unroll
            for (int off = 1; off < 16; off <<= 1) psum += __shfl_xor(psum, off, 16);
            l_run[i] = l_run[i] * corr + psum;
            m_run[i] = mnew;
#pragma unroll
            for (int j = 0; j < 4; ++j) O[i][j] *= corr;
        }
        // stash P
#pragma unroll
        for (int i = 0; i < 4; ++i) {
            float4 p4 = {pl[i][0], pl[i][1], pl[i][2], pl[i][3]};
            *(float4*)&Ps[ty * 4 + i][tx * 4] = p4;
        }
        __syncthreads();

        // O += P @ V
#pragma unroll
        for (int k = 0; k < 64; ++k) {
            float4 vv = *(const float4*)&Vs[k][tx * 4];
            float p0 = Ps[ty * 4 + 0][k];
            float p1 = Ps[ty * 4 + 1][k];
            float p2 = Ps[ty * 4 + 2][k];
            float p3 = Ps[ty * 4 + 3][k];
            O[0][0] += p0 * vv.x; O[0][1] += p0 * vv.y; O[0][2] += p0 * vv.z; O[0][3] += p0 * vv.w;
            O[1][0] += p1 * vv.x; O[1][1] += p1 * vv.y; O[1][2] += p1 * vv.z; O[1][3] += p1 * vv.w;
            O[2][0] += p2 * vv.x; O[2][1] += p2 * vv.y; O[2][2] += p2 * vv.z; O[2][3] += p2 * vv.w;
            O[3][0] += p3 * vv.x; O[3][1] += p3 * vv.y; O[3][2] += p3 * vv.z; O[3][3] += p3 * vv.w;
        }
    }

    const size_t baseO = ((size_t)(b * Tdim + qt * 64)) * Cdim + h * 64;
#pragma unroll
    for (int i = 0; i < 4; ++i) {
        float inv = 1.0f / l_run[i];
        float4 o4 = {O[i][0] * inv, O[i][1] * inv, O[i][2] * inv, O[i][3] * inv};
        *(float4*)(MO + baseO + (size_t)(ty * 4 + i) * Cdim + tx * 4) = o4;
    }
}

// ---------------------------------------------------------------------------
extern "C" void kernel_launch(void* const* d_in, const int* in_sizes, int n_in,
                              void* d_out, int out_size, void* d_ws, size_t ws_size,
                              hipStream_t stream) {
    const float* x   = (const float*)d_in[0];
    const float* Wq  = (const float*)d_in[1];
    const float* bq  = (const float*)d_in[2];
    const float* Wk  = (const float*)d_in[3];
    const float* bk  = (const float*)d_in[4];
    const float* Wv  = (const float*)d_in[5];
    const float* bv  = (const float*)d_in[6];
    const float* Wo  = (const float*)d_in[7];
    const float* bo  = (const float*)d_in[8];
    const float* Wr1 = (const float*)d_in[9];
    const float* br1 = (const float*)d_in[10];
    const float* Wr2 = (const float*)d_in[11];
    const float* br2 = (const float*)d_in[12];
    float* out = (float*)d_out;
    float* ws = (float*)d_ws;

    const size_t NTC = (size_t)Bdim * Tdim * Cdim;  // 4,194,304
    float* Qb   = ws;
    float* Kb   = ws + NTC;
    float* Vb   = ws + 2 * NTC;
    float* R1b  = ws + 3 * NTC;      // reused as MO after routing is computed
    float* MOb  = R1b;
    float* routing = ws + 4 * NTC;   // M_TOT*3 = 12288
    float* mvec = routing + 16384;   // [2][1024]
    float* tmp2 = mvec + 2048;       // [3][1024] (row2 = bv copy)
    float* cvec = tmp2 + 4096;       // [3][1024]: c2[b=0], c2[b=1], c3

    // --- constants path (tiny) ---
    hipMemsetAsync(mvec, 0, 2048 * sizeof(float), stream);
    colmean_kernel<<<dim3(Bdim, Cdim / 256, 8), 256, 0, stream>>>(x, mvec);
    gemv3_kernel<<<dim3(Cdim / 256, 2), 256, 0, stream>>>(mvec, Wv, bv, tmp2);
    copyvec_kernel<<<Cdim / 256, 256, 0, stream>>>(bv, tmp2 + 2 * Cdim);
    gemv3_kernel<<<dim3(Cdim / 256, 3), 256, 0, stream>>>(tmp2, Wo, bo, cvec);

    // --- projections ---
    dim3 gg(Cdim / 64, M_TOT / 64);
    gemm_f32<0><<<gg, 256, 0, stream>>>(x, Wq, bq, Qb, M_TOT, Cdim, Cdim, nullptr, nullptr);
    gemm_f32<0><<<gg, 256, 0, stream>>>(x, Wk, bk, Kb, M_TOT, Cdim, Cdim, nullptr, nullptr);
    gemm_f32<0><<<gg, 256, 0, stream>>>(x, Wv, bv, Vb, M_TOT, Cdim, Cdim, nullptr, nullptr);
    gemm_f32<1><<<gg, 256, 0, stream>>>(x, Wr1, br1, R1b, M_TOT, Cdim, Cdim, nullptr, nullptr);

    // --- routing gate (consumes R1b; after this R1b's space becomes MOb) ---
    routing_kernel<<<M_TOT / 4, 256, 0, stream>>>(R1b, Wr2, br2, routing);

    // --- flash attention (level 1) ---
    flash_f32<<<dim3(Bdim * Hdim, Tdim / 64), 256, 0, stream>>>(Qb, Kb, Vb, MOb);

    // --- output projection + routing combine ---
    gemm_f32<2><<<gg, 256, 0, stream>>>(MOb, Wo, bo, out, M_TOT, Cdim, Cdim, routing, cvec);
}

// Round 4
// 923.747 us; speedup vs baseline: 1.7762x; 1.7762x over previous
//
#include <hip/hip_runtime.h>
#include <hip/hip_bf16.h>
#include <math.h>

#define Bdim 2
#define Tdim 2048
#define Cdim 1024
#define Hdim 16
#define SCALE 0.125f
#define M_TOT (Bdim * Tdim)  // 4096
#define Kdim Cdim

typedef __attribute__((ext_vector_type(8))) short bf16x8;
typedef __attribute__((ext_vector_type(4))) float f32x4;
typedef unsigned short ushort_t;

__device__ __forceinline__ unsigned short f2bf(float f) {
    union { float f; unsigned u; } v; v.f = f;
    unsigned r = (v.u + 0x7FFFu + ((v.u >> 16) & 1u)) >> 16;
    return (unsigned short)r;
}
__device__ __forceinline__ float bf2f(unsigned short h) {
    union { unsigned u; float f; } v; v.u = ((unsigned)h) << 16;
    return v.f;
}

// ---------------------------------------------------------------------------
// Column mean over T: m[b][c] = (1/T) sum_t x[b,t,c].  grid (B, C/256, 8)
// ---------------------------------------------------------------------------
__global__ void colmean_kernel(const float* __restrict__ x, float* __restrict__ m) {
    int b = blockIdx.x;
    int c = blockIdx.y * 256 + threadIdx.x;
    int t0 = blockIdx.z * 256;
    float s = 0.f;
    for (int t = t0; t < t0 + 256; ++t)
        s += x[((size_t)b * Tdim + t) * Cdim + c];
    atomicAdd(&m[b * Cdim + c], s * (1.0f / Tdim));
}

// out[r][c] = sum_k rows[r][k] * W[k][c] + bias[c].   grid (C/256, R)
__global__ void gemv3_kernel(const float* __restrict__ rows, const float* __restrict__ W,
                             const float* __restrict__ bias, float* __restrict__ out) {
    int c = blockIdx.x * 256 + threadIdx.x;
    int r = blockIdx.y;
    const float* rp = rows + (size_t)r * Cdim;
    float s = 0.f;
    for (int k = 0; k < Cdim; ++k)
        s += rp[k] * W[(size_t)k * Cdim + c];
    out[(size_t)r * Cdim + c] = s + bias[c];
}

__global__ void copyvec_kernel(const float* __restrict__ src, float* __restrict__ dst) {
    int i = blockIdx.x * 256 + threadIdx.x;
    dst[i] = src[i];
}

// ---------------------------------------------------------------------------
// fp32 -> bf16 cast, 4 elems/thread
// ---------------------------------------------------------------------------
__global__ void cast_bf16_kernel(const float* __restrict__ in, ushort_t* __restrict__ out) {
    int i = blockIdx.x * 256 + threadIdx.x;
    float4 v = ((const float4*)in)[i];
    ushort4 o;
    o.x = f2bf(v.x); o.y = f2bf(v.y); o.z = f2bf(v.z); o.w = f2bf(v.w);
    ((ushort4*)out)[i] = o;
}

// ---------------------------------------------------------------------------
// W [K][N] fp32 -> Wt [N][K] bf16.  64x64 tiles, grid (N/64, K/64)
// ---------------------------------------------------------------------------
__global__ __launch_bounds__(256) void transpose_cast_kernel(const float* __restrict__ W,
                                                             ushort_t* __restrict__ Wt) {
    __shared__ float L[64][65];
    int n0 = blockIdx.x * 64, k0 = blockIdx.y * 64;
    int t = threadIdx.x;
    int c4 = (t & 15) * 4, rr = t >> 4;
#pragma unroll
    for (int i = 0; i < 4; ++i) {
        int k = rr + i * 16;
        float4 v = *(const float4*)(W + (size_t)(k0 + k) * Cdim + n0 + c4);
        L[k][c4 + 0] = v.x; L[k][c4 + 1] = v.y; L[k][c4 + 2] = v.z; L[k][c4 + 3] = v.w;
    }
    __syncthreads();
#pragma unroll
    for (int i = 0; i < 4; ++i) {
        int n = rr + i * 16;
        ushort4 o;
        o.x = f2bf(L[c4 + 0][n]); o.y = f2bf(L[c4 + 1][n]);
        o.z = f2bf(L[c4 + 2][n]); o.w = f2bf(L[c4 + 3][n]);
        *(ushort4*)(Wt + (size_t)(n0 + n) * Kdim + k0 + c4) = o;
    }
}

// ---------------------------------------------------------------------------
// bf16 MFMA GEMM: C[M,N] = A[M,K] @ Bt[N,K]^T + bias (+epilogue)
// tile 64(M) x 128(N), BK=64, 4 waves (2x2), each wave 32x64 = 2x4 16x16 frags.
// Double-buffered LDS via global_load_lds(16B); 16B-chunk XOR swizzle
// chunk' = chunk ^ ((row>>1)&7) applied on SOURCE (staging) and READ (rule 21).
// MODE 0: bf16 out + bias   MODE 1: f32 tanh(out+bias)   MODE 2: routing combine f32
// ---------------------------------------------------------------------------
__device__ __forceinline__ void stage_tile(const ushort_t* __restrict__ A,
                                           const ushort_t* __restrict__ Bt,
                                           ushort_t* ldsbuf, int m0, int n0, int kel,
                                           int wid, int lane) {
#pragma unroll
    for (int i = 0; i < 2; ++i) {
        int c = wid * 128 + i * 64 + lane;
        int row = c >> 3;
        int gch = (c & 7) ^ ((c >> 4) & 7);
        const ushort_t* g = A + (size_t)(m0 + row) * Kdim + kel + gch * 8;
        __builtin_amdgcn_global_load_lds(
            (const __attribute__((address_space(1))) unsigned int*)g,
            (__attribute__((address_space(3))) unsigned int*)(ldsbuf + (wid * 128 + i * 64) * 8),
            16, 0, 0);
    }
#pragma unroll
    for (int i = 0; i < 4; ++i) {
        int c = wid * 256 + i * 64 + lane;
        int row = c >> 3;
        int gch = (c & 7) ^ ((c >> 4) & 7);
        const ushort_t* g = Bt + (size_t)(n0 + row) * Kdim + kel + gch * 8;
        __builtin_amdgcn_global_load_lds(
            (const __attribute__((address_space(1))) unsigned int*)g,
            (__attribute__((address_space(3))) unsigned int*)(ldsbuf + 4096 + (wid * 256 + i * 64) * 8),
            16, 0, 0);
    }
}

template <int MODE>
__global__ __launch_bounds__(256) void gemm_bf16(
    const ushort_t* __restrict__ A, const ushort_t* __restrict__ Bt,
    const float* __restrict__ bias, void* __restrict__ Cout,
    const float* __restrict__ routing, const float* __restrict__ cvec) {
    __shared__ ushort_t lds[2 * 12288];  // per buf: A 64x64 (4096) + B 128x64 (8192)

    int tid = threadIdx.x, lane = tid & 63, wid = tid >> 6;
    int wm = wid >> 1, wn = wid & 1;
    int m0 = blockIdx.y * 64, n0 = blockIdx.x * 128;

    f32x4 acc[2][4];
    f32x4 z = {0.f, 0.f, 0.f, 0.f};
#pragma unroll
    for (int mi = 0; mi < 2; ++mi)
#pragma unroll
        for (int ni = 0; ni < 4; ++ni) acc[mi][ni] = z;

    stage_tile(A, Bt, lds, m0, n0, 0, wid, lane);
    __syncthreads();  // drains vmcnt(0): buf0 ready

    int cur = 0;
    for (int t = 0; t < 16; ++t) {
        if (t < 15) stage_tile(A, Bt, lds + (cur ^ 1) * 12288, m0, n0, (t + 1) * 64, wid, lane);
        const ushort_t* Ab = lds + cur * 12288;
        const ushort_t* Bb = Ab + 4096;
#pragma unroll
        for (int s = 0; s < 2; ++s) {
            int kc = (lane >> 4) + s * 4;
            bf16x8 af[2], bfr[4];
#pragma unroll
            for (int mi = 0; mi < 2; ++mi) {
                int row = wm * 32 + mi * 16 + (lane & 15);
                int ch = kc ^ ((row >> 1) & 7);
                af[mi] = *(const bf16x8*)(Ab + row * 64 + ch * 8);
            }
#pragma unroll
            for (int ni = 0; ni < 4; ++ni) {
                int row = wn * 64 + ni * 16 + (lane & 15);
                int ch = kc ^ ((row >> 1) & 7);
                bfr[ni] = *(const bf16x8*)(Bb + row * 64 + ch * 8);
            }
#pragma unroll
            for (int mi = 0; mi < 2; ++mi)
#pragma unroll
                for (int ni = 0; ni < 4; ++ni)
                    acc[mi][ni] = __builtin_amdgcn_mfma_f32_16x16x32_bf16(
                        af[mi], bfr[ni], acc[mi][ni], 0, 0, 0);
        }
        __syncthreads();  // all reads of cur done + next-buf loads landed
        cur ^= 1;
    }

#pragma unroll
    for (int mi = 0; mi < 2; ++mi)
#pragma unroll
        for (int ni = 0; ni < 4; ++ni) {
            int col = n0 + wn * 64 + ni * 16 + (lane & 15);
            float bs = bias[col];
#pragma unroll
            for (int q = 0; q < 4; ++q) {
                int row = m0 + wm * 32 + mi * 16 + (lane >> 4) * 4 + q;
                float v = acc[mi][ni][q] + bs;
                if constexpr (MODE == 0) {
                    ((ushort_t*)Cout)[(size_t)row * Cdim + col] = f2bf(v);
                } else if constexpr (MODE == 1) {
                    ((float*)Cout)[(size_t)row * Cdim + col] = tanhf(v);
                } else {
                    int b = row >> 11;
                    float r0 = routing[row * 3 + 0];
                    float r1 = routing[row * 3 + 1];
                    float r2 = routing[row * 3 + 2];
                    ((float*)Cout)[(size_t)row * Cdim + col] =
                        r0 * v + r1 * cvec[b * Cdim + col] + r2 * cvec[2 * Cdim + col];
                }
            }
        }
}

// ---------------------------------------------------------------------------
// Routing: logits = R1 @ Wr2 + br2; softmax over 3. One wave per row.
// ---------------------------------------------------------------------------
__global__ __launch_bounds__(256) void routing_kernel(
    const float* __restrict__ R1, const float* __restrict__ Wr2,
    const float* __restrict__ br2, float* __restrict__ routing) {
    int wid = threadIdx.x >> 6, lane = threadIdx.x & 63;
    int row = blockIdx.x * 4 + wid;
    const float* rp = R1 + (size_t)row * Cdim;
    float a0 = 0.f, a1 = 0.f, a2 = 0.f;
    for (int k = lane; k < Cdim; k += 64) {
        float xv = rp[k];
        a0 += xv * Wr2[k * 3 + 0];
        a1 += xv * Wr2[k * 3 + 1];
        a2 += xv * Wr2[k * 3 + 2];
    }
#pragma unroll
    for (int off = 32; off; off >>= 1) {
        a0 += __shfl_xor(a0, off);
        a1 += __shfl_xor(a1, off);
        a2 += __shfl_xor(a2, off);
    }
    if (lane == 0) {
        a0 += br2[0]; a1 += br2[1]; a2 += br2[2];
        float mx = fmaxf(a0, fmaxf(a1, a2));
        float e0 = __expf(a0 - mx), e1 = __expf(a1 - mx), e2 = __expf(a2 - mx);
        float inv = 1.0f / (e0 + e1 + e2);
        routing[row * 3 + 0] = e0 * inv;
        routing[row * 3 + 1] = e1 * inv;
        routing[row * 3 + 2] = e2 * inv;
    }
}

// ---------------------------------------------------------------------------
// Flash attention (bf16 in, fp32 math, bf16 out). grid (B*H, T/64), block 256.
// LDS stride 64 + XOR swizzle col^=4*((row>>2)&7) -> hot K-read 8-way -> 2-way.
// ---------------------------------------------------------------------------
#define SWZ(r) (4 * (((r) >> 2) & 7))

__global__ __launch_bounds__(256) void flash_f32(
    const ushort_t* __restrict__ Qg, const ushort_t* __restrict__ Kg,
    const ushort_t* __restrict__ Vg, ushort_t* __restrict__ MO) {
    __shared__ float Qs[64][64];
    __shared__ float Ks[64][64];
    __shared__ float Vs[64][64];
    __shared__ float Ps[64][64];

    int bh = blockIdx.x;
    int b = bh >> 4, h = bh & 15;
    int qt = blockIdx.y;
    int tid = threadIdx.x;
    int tx = tid & 15, ty = tid >> 4;

    const size_t baseQ = ((size_t)(b * Tdim + qt * 64)) * Cdim + h * 64;
#pragma unroll
    for (int it = 0; it < 4; ++it) {
        int r = ty + it * 16;
        ushort4 qv = *(const ushort4*)(Qg + baseQ + (size_t)r * Cdim + tx * 4);
        float4 qf = {bf2f(qv.x), bf2f(qv.y), bf2f(qv.z), bf2f(qv.w)};
        *(float4*)&Qs[r][(tx * 4) ^ SWZ(r)] = qf;
    }

    float m_run[4], l_run[4], O[4][4];
#pragma unroll
    for (int i = 0; i < 4; ++i) {
        m_run[i] = -1e30f;
        l_run[i] = 0.f;
#pragma unroll
        for (int j = 0; j < 4; ++j) O[i][j] = 0.f;
    }

    for (int kt = 0; kt < Tdim / 64; ++kt) {
        const size_t baseK = ((size_t)(b * Tdim + kt * 64)) * Cdim + h * 64;
        ushort4 kreg[4], vreg[4];
#pragma unroll
        for (int it = 0; it < 4; ++it) {
            int r = ty + it * 16;
            kreg[it] = *(const ushort4*)(Kg + baseK + (size_t)r * Cdim + tx * 4);
            vreg[it] = *(const ushort4*)(Vg + baseK + (size_t)r * Cdim + tx * 4);
        }
        __syncthreads();  // everyone done reading Ks/Vs/Ps of previous tile
#pragma unroll
        for (int it = 0; it < 4; ++it) {
            int r = ty + it * 16;
            float4 kf = {bf2f(kreg[it].x), bf2f(kreg[it].y), bf2f(kreg[it].z), bf2f(kreg[it].w)};
            float4 vf = {bf2f(vreg[it].x), bf2f(vreg[it].y), bf2f(vreg[it].z), bf2f(vreg[it].w)};
            *(float4*)&Ks[r][(tx * 4) ^ SWZ(r)] = kf;
            *(float4*)&Vs[r][(tx * 4) ^ SWZ(r)] = vf;
        }
        __syncthreads();

        // S = Q K^T * SCALE  (4x4 per thread)
        float s[4][4] = {};
#pragma unroll
        for (int k4 = 0; k4 < 64; k4 += 4) {
            float4 qa[4], kb[4];
#pragma unroll
            for (int i = 0; i < 4; ++i) qa[i] = *(const float4*)&Qs[ty * 4 + i][k4 ^ SWZ(ty * 4 + i)];
#pragma unroll
            for (int j = 0; j < 4; ++j) kb[j] = *(const float4*)&Ks[tx * 4 + j][k4 ^ SWZ(tx * 4 + j)];
#pragma unroll
            for (int i = 0; i < 4; ++i)
#pragma unroll
                for (int j = 0; j < 4; ++j)
                    s[i][j] += qa[i].x * kb[j].x + qa[i].y * kb[j].y +
                               qa[i].z * kb[j].z + qa[i].w * kb[j].w;
        }

        // online softmax update
        float pl[4][4];
#pragma unroll
        for (int i = 0; i < 4; ++i) {
#pragma unroll
            for (int j = 0; j < 4; ++j) s[i][j] *= SCALE;
            float mx = fmaxf(fmaxf(s[i][0], s[i][1]), fmaxf(s[i][2], s[i][3]));
#pragma unroll
            for (int off = 1; off < 16; off <<= 1) mx = fmaxf(mx, __shfl_xor(mx, off, 16));
            float mnew = fmaxf(m_run[i], mx);
            float corr = __expf(m_run[i] - mnew);
            float psum = 0.f;
#pragma unroll
            for (int j = 0; j < 4; ++j) {
                pl[i][j] = __expf(s[i][j] - mnew);
                psum += pl[i][j];
            }
#pragma unroll
            for (int off = 1; off < 16; off <<= 1) psum += __shfl_xor(psum, off, 16);
            l_run[i] = l_run[i] * corr + psum;
            m_run[i] = mnew;
#pragma unroll
            for (int j = 0; j < 4; ++j) O[i][j] *= corr;
        }
        // stash P
#pragma unroll
        for (int i = 0; i < 4; ++i) {
            float4 p4 = {pl[i][0], pl[i][1], pl[i][2], pl[i][3]};
            *(float4*)&Ps[ty * 4 + i][(tx * 4) ^ SWZ(ty * 4 + i)] = p4;
        }
        __syncthreads();

        // O += P @ V
#pragma unroll
        for (int k = 0; k < 64; ++k) {
            float4 vv = *(const float4*)&Vs[k][(tx * 4) ^ SWZ(k)];
            float p0 = Ps[ty * 4 + 0][k ^ SWZ(ty * 4 + 0)];
            float p1 = Ps[ty * 4 + 1][k ^ SWZ(ty * 4 + 1)];
            float p2 = Ps[ty * 4 + 2][k ^ SWZ(ty * 4 + 2)];
            float p3 = Ps[ty * 4 + 3][k ^ SWZ(ty * 4 + 3)];
            O[0][0] += p0 * vv.x; O[0][1] += p0 * vv.y; O[0][2] += p0 * vv.z; O[0][3] += p0 * vv.w;
            O[1][0] += p1 * vv.x; O[1][1] += p1 * vv.y; O[1][2] += p1 * vv.z; O[1][3] += p1 * vv.w;
            O[2][0] += p2 * vv.x; O[2][1] += p2 * vv.y; O[2][2] += p2 * vv.z; O[2][3] += p2 * vv.w;
            O[3][0] += p3 * vv.x; O[3][1] += p3 * vv.y; O[3][2] += p3 * vv.z; O[3][3] += p3 * vv.w;
        }
    }

    const size_t baseO = ((size_t)(b * Tdim + qt * 64)) * Cdim + h * 64;
#pragma unroll
    for (int i = 0; i < 4; ++i) {
        float inv = 1.0f / l_run[i];
        ushort4 o4;
        o4.x = f2bf(O[i][0] * inv); o4.y = f2bf(O[i][1] * inv);
        o4.z = f2bf(O[i][2] * inv); o4.w = f2bf(O[i][3] * inv);
        *(ushort4*)(MO + baseO + (size_t)(ty * 4 + i) * Cdim + tx * 4) = o4;
    }
}

// ---------------------------------------------------------------------------
extern "C" void kernel_launch(void* const* d_in, const int* in_sizes, int n_in,
                              void* d_out, int out_size, void* d_ws, size_t ws_size,
                              hipStream_t stream) {
    const float* x   = (const float*)d_in[0];
    const float* Wq  = (const float*)d_in[1];
    const float* bq  = (const float*)d_in[2];
    const float* Wk  = (const float*)d_in[3];
    const float* bk  = (const float*)d_in[4];
    const float* Wv  = (const float*)d_in[5];
    const float* bv  = (const float*)d_in[6];
    const float* Wo  = (const float*)d_in[7];
    const float* bo  = (const float*)d_in[8];
    const float* Wr1 = (const float*)d_in[9];
    const float* br1 = (const float*)d_in[10];
    const float* Wr2 = (const float*)d_in[11];
    const float* br2 = (const float*)d_in[12];
    float* out = (float*)d_out;
    float* ws = (float*)d_ws;

    const size_t MF = 1024 * 1024;  // 1M floats
    ushort_t* Qb  = (ushort_t*)ws;                    // 4M bf16 = 2MF
    ushort_t* Kb  = (ushort_t*)(ws + 2 * MF);         // 2MF
    ushort_t* Vb  = (ushort_t*)(ws + 4 * MF);         // 2MF
    float*    R1b = ws + 6 * MF;                      // 4MF f32
    ushort_t* MOb = (ushort_t*)(ws + 6 * MF);         // aliases R1b (dead after routing)
    ushort_t* xb  = (ushort_t*)(ws + 10 * MF);        // 2MF
    ushort_t* Wqt  = (ushort_t*)(ws + 12 * MF);       // 0.5MF each
    ushort_t* Wkt  = (ushort_t*)(ws + 12 * MF + 512 * 1024);
    ushort_t* Wvt  = (ushort_t*)(ws + 13 * MF);
    ushort_t* Wr1t = (ushort_t*)(ws + 13 * MF + 512 * 1024);
    ushort_t* Wot  = (ushort_t*)(ws + 14 * MF);
    float* routing = ws + 14 * MF + 512 * 1024;       // 12288 f
    float* mvec = routing + 12288;                    // 2048 f
    float* tmp2 = mvec + 2048;                        // 3072 f
    float* cvec = tmp2 + 3072;                        // 3072 f

    // --- constants path (tiny, fp32) ---
    hipMemsetAsync(mvec, 0, 2048 * sizeof(float), stream);
    colmean_kernel<<<dim3(Bdim, Cdim / 256, 8), 256, 0, stream>>>(x, mvec);
    gemv3_kernel<<<dim3(Cdim / 256, 2), 256, 0, stream>>>(mvec, Wv, bv, tmp2);
    copyvec_kernel<<<Cdim / 256, 256, 0, stream>>>(bv, tmp2 + 2 * Cdim);
    gemv3_kernel<<<dim3(Cdim / 256, 3), 256, 0, stream>>>(tmp2, Wo, bo, cvec);

    // --- casts / transposes ---
    cast_bf16_kernel<<<4096, 256, 0, stream>>>(x, xb);
    dim3 tg(16, 16);
    transpose_cast_kernel<<<tg, 256, 0, stream>>>(Wq, Wqt);
    transpose_cast_kernel<<<tg, 256, 0, stream>>>(Wk, Wkt);
    transpose_cast_kernel<<<tg, 256, 0, stream>>>(Wv, Wvt);
    transpose_cast_kernel<<<tg, 256, 0, stream>>>(Wr1, Wr1t);
    transpose_cast_kernel<<<tg, 256, 0, stream>>>(Wo, Wot);

    // --- projections (bf16 MFMA) ---
    dim3 gg(Cdim / 128, M_TOT / 64);  // (8, 64) = 512 blocks
    gemm_bf16<0><<<gg, 256, 0, stream>>>(xb, Wqt, bq, Qb, nullptr, nullptr);
    gemm_bf16<0><<<gg, 256, 0, stream>>>(xb, Wkt, bk, Kb, nullptr, nullptr);
    gemm_bf16<0><<<gg, 256, 0, stream>>>(xb, Wvt, bv, Vb, nullptr, nullptr);
    gemm_bf16<1><<<gg, 256, 0, stream>>>(xb, Wr1t, br1, R1b, nullptr, nullptr);

    // --- routing gate (consumes R1b; afterwards its space becomes MOb) ---
    routing_kernel<<<M_TOT / 4, 256, 0, stream>>>(R1b, Wr2, br2, routing);

    // --- flash attention (level 1) ---
    flash_f32<<<dim3(Bdim * Hdim, Tdim / 64), 256, 0, stream>>>(Qb, Kb, Vb, MOb);

    // --- output projection + routing combine ---
    gemm_bf16<2><<<gg, 256, 0, stream>>>(MOb, Wot, bo, (void*)out, routing, cvec);
}

// Round 5
// 326.045 us; speedup vs baseline: 5.0323x; 2.8332x over previous
//
#include <hip/hip_runtime.h>
#include <hip/hip_bf16.h>
#include <math.h>

#define Bdim 2
#define Tdim 2048
#define Cdim 1024
#define Hdim 16
#define SCALE 0.125f
#define M_TOT (Bdim * Tdim)  // 4096
#define Kdim Cdim
#define KVB 64

typedef __attribute__((ext_vector_type(8))) short bf16x8;
typedef __attribute__((ext_vector_type(4))) float f32x4;
typedef unsigned short ushort_t;

union U8 { bf16x8 v; ushort4 u4[2]; };

__device__ __forceinline__ unsigned short f2bf(float f) {
    union { float f; unsigned u; } v; v.f = f;
    unsigned r = (v.u + 0x7FFFu + ((v.u >> 16) & 1u)) >> 16;
    return (unsigned short)r;
}
__device__ __forceinline__ float bf2f(unsigned short h) {
    union { unsigned u; float f; } v; v.u = ((unsigned)h) << 16;
    return v.f;
}

// DPP 16-lane reductions (VALU pipe, no LDS traffic).
template <int CTRL>
__device__ __forceinline__ float dppf(float v) {
    int r = __builtin_amdgcn_update_dpp(0, __builtin_bit_cast(int, v), CTRL, 0xF, 0xF, false);
    return __builtin_bit_cast(float, r);
}
__device__ __forceinline__ float rmax16(float v) {
    v = fmaxf(v, dppf<0xB1>(v));   // quad_perm xor1
    v = fmaxf(v, dppf<0x4E>(v));   // quad_perm xor2
    v = fmaxf(v, dppf<0x124>(v));  // row_ror:4
    v = fmaxf(v, dppf<0x128>(v));  // row_ror:8
    return v;
}
__device__ __forceinline__ float rsum16(float v) {
    v += dppf<0xB1>(v);
    v += dppf<0x4E>(v);
    v += dppf<0x124>(v);
    v += dppf<0x128>(v);
    return v;
}

// ---------------------------------------------------------------------------
// Column mean over T: m[b][c] += partial.  grid (B, C/256, 32)
// ---------------------------------------------------------------------------
__global__ void colmean_kernel(const float* __restrict__ x, float* __restrict__ m) {
    int b = blockIdx.x;
    int c = blockIdx.y * 256 + threadIdx.x;
    int t0 = blockIdx.z * 64;
    float s = 0.f;
    for (int t = t0; t < t0 + 64; ++t)
        s += x[((size_t)b * Tdim + t) * Cdim + c];
    atomicAdd(&m[b * Cdim + c], s * (1.0f / Tdim));
}

// out rows 0..R-1 = bias broadcast. grid (C/256)
__global__ void biasinit_kernel(const float* __restrict__ bias, float* __restrict__ out, int R) {
    int c = blockIdx.x * 256 + threadIdx.x;
    for (int r = 0; r < R; ++r) out[(size_t)r * Cdim + c] = bias[c];
}

// out[r][c] += sum over K-slice of rows[r][k]*W[k][c].  grid (C/256, R, 8)
__global__ void gemv3_part_kernel(const float* __restrict__ rows, const float* __restrict__ W,
                                  float* __restrict__ out) {
    int c = blockIdx.x * 256 + threadIdx.x;
    int r = blockIdx.y;
    int k0 = blockIdx.z * 128;
    const float* rp = rows + (size_t)r * Cdim;
    float s = 0.f;
    for (int k = k0; k < k0 + 128; ++k)
        s += rp[k] * W[(size_t)k * Cdim + c];
    atomicAdd(&out[(size_t)r * Cdim + c], s);
}

// ---------------------------------------------------------------------------
// fp32 -> bf16 cast, 4 elems/thread
// ---------------------------------------------------------------------------
__global__ void cast_bf16_kernel(const float* __restrict__ in, ushort_t* __restrict__ out) {
    int i = blockIdx.x * 256 + threadIdx.x;
    float4 v = ((const float4*)in)[i];
    ushort4 o;
    o.x = f2bf(v.x); o.y = f2bf(v.y); o.z = f2bf(v.z); o.w = f2bf(v.w);
    ((ushort4*)out)[i] = o;
}

// ---------------------------------------------------------------------------
// W [K][N] fp32 -> Wt [N][K] bf16.  64x64 tiles, grid (N/64, K/64)
// ---------------------------------------------------------------------------
__global__ __launch_bounds__(256) void transpose_cast_kernel(const float* __restrict__ W,
                                                             ushort_t* __restrict__ Wt) {
    __shared__ float L[64][65];
    int n0 = blockIdx.x * 64, k0 = blockIdx.y * 64;
    int t = threadIdx.x;
    int c4 = (t & 15) * 4, rr = t >> 4;
#pragma unroll
    for (int i = 0; i < 4; ++i) {
        int k = rr + i * 16;
        float4 v = *(const float4*)(W + (size_t)(k0 + k) * Cdim + n0 + c4);
        L[k][c4 + 0] = v.x; L[k][c4 + 1] = v.y; L[k][c4 + 2] = v.z; L[k][c4 + 3] = v.w;
    }
    __syncthreads();
#pragma unroll
    for (int i = 0; i < 4; ++i) {
        int n = rr + i * 16;
        ushort4 o;
        o.x = f2bf(L[c4 + 0][n]); o.y = f2bf(L[c4 + 1][n]);
        o.z = f2bf(L[c4 + 2][n]); o.w = f2bf(L[c4 + 3][n]);
        *(ushort4*)(Wt + (size_t)(n0 + n) * Kdim + k0 + c4) = o;
    }
}

// ---------------------------------------------------------------------------
// Vb [B*T][C] bf16 -> Vt [(b*H+h)*64 + d][T] bf16 (per-head transpose).
// grid (B*H, T/64)
// ---------------------------------------------------------------------------
__global__ __launch_bounds__(256) void transpose_v_kernel(const ushort_t* __restrict__ Vb,
                                                          ushort_t* __restrict__ Vt) {
    __shared__ ushort_t L[64][72];
    int bh = blockIdx.x, tt = blockIdx.y;
    int b = bh >> 4, h = bh & 15;
    int t = threadIdx.x;
    int tx = t & 15, ty = t >> 4;
#pragma unroll
    for (int it = 0; it < 4; ++it) {
        int tok = ty + it * 16;
        ushort4 v = *(const ushort4*)(Vb + ((size_t)(b * Tdim + tt * 64 + tok)) * Cdim + h * 64 + tx * 4);
        *(ushort4*)&L[tok][tx * 4] = v;
    }
    __syncthreads();
#pragma unroll
    for (int it = 0; it < 4; ++it) {
        int d = ty + it * 16;
        ushort4 o;
        o.x = L[tx * 4 + 0][d]; o.y = L[tx * 4 + 1][d];
        o.z = L[tx * 4 + 2][d]; o.w = L[tx * 4 + 3][d];
        *(ushort4*)(Vt + ((size_t)(bh * 64 + d)) * Tdim + tt * 64 + tx * 4) = o;
    }
}

// ---------------------------------------------------------------------------
// bf16 MFMA GEMM: C[M,N] = A[M,K] @ Bt[N,K]^T + bias (+epilogue)  (round-4, proven)
// ---------------------------------------------------------------------------
__device__ __forceinline__ void stage_tile(const ushort_t* __restrict__ A,
                                           const ushort_t* __restrict__ Bt,
                                           ushort_t* ldsbuf, int m0, int n0, int kel,
                                           int wid, int lane) {
#pragma unroll
    for (int i = 0; i < 2; ++i) {
        int c = wid * 128 + i * 64 + lane;
        int row = c >> 3;
        int gch = (c & 7) ^ ((c >> 4) & 7);
        const ushort_t* g = A + (size_t)(m0 + row) * Kdim + kel + gch * 8;
        __builtin_amdgcn_global_load_lds(
            (const __attribute__((address_space(1))) unsigned int*)g,
            (__attribute__((address_space(3))) unsigned int*)(ldsbuf + (wid * 128 + i * 64) * 8),
            16, 0, 0);
    }
#pragma unroll
    for (int i = 0; i < 4; ++i) {
        int c = wid * 256 + i * 64 + lane;
        int row = c >> 3;
        int gch = (c & 7) ^ ((c >> 4) & 7);
        const ushort_t* g = Bt + (size_t)(n0 + row) * Kdim + kel + gch * 8;
        __builtin_amdgcn_global_load_lds(
            (const __attribute__((address_space(1))) unsigned int*)g,
            (__attribute__((address_space(3))) unsigned int*)(ldsbuf + 4096 + (wid * 256 + i * 64) * 8),
            16, 0, 0);
    }
}

template <int MODE>
__global__ __launch_bounds__(256) void gemm_bf16(
    const ushort_t* __restrict__ A, const ushort_t* __restrict__ Bt,
    const float* __restrict__ bias, void* __restrict__ Cout,
    const float* __restrict__ routing, const float* __restrict__ cvec) {
    __shared__ ushort_t lds[2 * 12288];  // per buf: A 64x64 (4096) + B 128x64 (8192)

    int tid = threadIdx.x, lane = tid & 63, wid = tid >> 6;
    int wm = wid >> 1, wn = wid & 1;
    int m0 = blockIdx.y * 64, n0 = blockIdx.x * 128;

    f32x4 acc[2][4];
    f32x4 z = {0.f, 0.f, 0.f, 0.f};
#pragma unroll
    for (int mi = 0; mi < 2; ++mi)
#pragma unroll
        for (int ni = 0; ni < 4; ++ni) acc[mi][ni] = z;

    stage_tile(A, Bt, lds, m0, n0, 0, wid, lane);
    __syncthreads();

    int cur = 0;
    for (int t = 0; t < 16; ++t) {
        if (t < 15) stage_tile(A, Bt, lds + (cur ^ 1) * 12288, m0, n0, (t + 1) * 64, wid, lane);
        const ushort_t* Ab = lds + cur * 12288;
        const ushort_t* Bb = Ab + 4096;
#pragma unroll
        for (int s = 0; s < 2; ++s) {
            int kc = (lane >> 4) + s * 4;
            bf16x8 af[2], bfr[4];
#pragma unroll
            for (int mi = 0; mi < 2; ++mi) {
                int row = wm * 32 + mi * 16 + (lane & 15);
                int ch = kc ^ ((row >> 1) & 7);
                af[mi] = *(const bf16x8*)(Ab + row * 64 + ch * 8);
            }
#pragma unroll
            for (int ni = 0; ni < 4; ++ni) {
                int row = wn * 64 + ni * 16 + (lane & 15);
                int ch = kc ^ ((row >> 1) & 7);
                bfr[ni] = *(const bf16x8*)(Bb + row * 64 + ch * 8);
            }
#pragma unroll
            for (int mi = 0; mi < 2; ++mi)
#pragma unroll
                for (int ni = 0; ni < 4; ++ni)
                    acc[mi][ni] = __builtin_amdgcn_mfma_f32_16x16x32_bf16(
                        af[mi], bfr[ni], acc[mi][ni], 0, 0, 0);
        }
        __syncthreads();
        cur ^= 1;
    }

#pragma unroll
    for (int mi = 0; mi < 2; ++mi)
#pragma unroll
        for (int ni = 0; ni < 4; ++ni) {
            int col = n0 + wn * 64 + ni * 16 + (lane & 15);
            float bs = bias[col];
#pragma unroll
            for (int q = 0; q < 4; ++q) {
                int row = m0 + wm * 32 + mi * 16 + (lane >> 4) * 4 + q;
                float v = acc[mi][ni][q] + bs;
                if constexpr (MODE == 0) {
                    ((ushort_t*)Cout)[(size_t)row * Cdim + col] = f2bf(v);
                } else if constexpr (MODE == 1) {
                    ((float*)Cout)[(size_t)row * Cdim + col] = tanhf(v);
                } else {
                    int b = row >> 11;
                    float r0 = routing[row * 3 + 0];
                    float r1 = routing[row * 3 + 1];
                    float r2 = routing[row * 3 + 2];
                    ((float*)Cout)[(size_t)row * Cdim + col] =
                        r0 * v + r1 * cvec[b * Cdim + col] + r2 * cvec[2 * Cdim + col];
                }
            }
        }
}

// ---------------------------------------------------------------------------
// Routing: logits = R1 @ Wr2 + br2; softmax over 3. One wave per row.
// ---------------------------------------------------------------------------
__global__ __launch_bounds__(256) void routing_kernel(
    const float* __restrict__ R1, const float* __restrict__ Wr2,
    const float* __restrict__ br2, float* __restrict__ routing) {
    int wid = threadIdx.x >> 6, lane = threadIdx.x & 63;
    int row = blockIdx.x * 4 + wid;
    const float* rp = R1 + (size_t)row * Cdim;
    float a0 = 0.f, a1 = 0.f, a2 = 0.f;
    for (int k = lane; k < Cdim; k += 64) {
        float xv = rp[k];
        a0 += xv * Wr2[k * 3 + 0];
        a1 += xv * Wr2[k * 3 + 1];
        a2 += xv * Wr2[k * 3 + 2];
    }
#pragma unroll
    for (int off = 32; off; off >>= 1) {
        a0 += __shfl_xor(a0, off);
        a1 += __shfl_xor(a1, off);
        a2 += __shfl_xor(a2, off);
    }
    if (lane == 0) {
        a0 += br2[0]; a1 += br2[1]; a2 += br2[2];
        float mx = fmaxf(a0, fmaxf(a1, a2));
        float e0 = __expf(a0 - mx), e1 = __expf(a1 - mx), e2 = __expf(a2 - mx);
        float inv = 1.0f / (e0 + e1 + e2);
        routing[row * 3 + 0] = e0 * inv;
        routing[row * 3 + 1] = e1 * inv;
        routing[row * 3 + 2] = e2 * inv;
    }
}

// ---------------------------------------------------------------------------
// MFMA flash attention. grid (B*H, T/128), block 256 (4 waves x 32 q-rows).
// K staged [key][d], V staged pre-transposed [d][key]; both chunk-XOR swizzled.
// P via per-wave LDS (stride 68 ushorts: b16 writes conflict-free, b64 reads
// bank-uniform, 8B aligned). Softmax row-reduce via DPP (VALU pipe).
// ---------------------------------------------------------------------------
__global__ __launch_bounds__(256) void flash_mfma(
    const ushort_t* __restrict__ Qg, const ushort_t* __restrict__ Kg,
    const ushort_t* __restrict__ Vtg, ushort_t* __restrict__ MO) {
    __shared__ ushort_t KVs[2][2][64 * 64];  // [buf][K=0 / Vt=1]
    __shared__ ushort_t Ps[4][32 * 68];

    int tid = threadIdx.x, lane = tid & 63, wid = tid >> 6;
    int tx = lane & 15, g = lane >> 4;
    int bh = blockIdx.x, b = bh >> 4, h = bh & 15;
    int qt = blockIdx.y;

    // Q fragments in registers: A-frag lane: m = tx, k = g*8 + s*32
    bf16x8 qf[2][2];
#pragma unroll
    for (int mi = 0; mi < 2; ++mi)
#pragma unroll
        for (int s = 0; s < 2; ++s) {
            int row = qt * 128 + wid * 32 + mi * 16 + tx;
            qf[mi][s] = *(const bf16x8*)(Qg + ((size_t)(b * Tdim + row)) * Cdim + h * 64 + s * 32 + g * 8);
        }

    f32x4 accO[2][4];
    f32x4 z = {0.f, 0.f, 0.f, 0.f};
    float m_run[2][4], l_run[2][4];
#pragma unroll
    for (int mi = 0; mi < 2; ++mi) {
#pragma unroll
        for (int df = 0; df < 4; ++df) accO[mi][df] = z;
#pragma unroll
        for (int q = 0; q < 4; ++q) { m_run[mi][q] = -1e30f; l_run[mi][q] = 0.f; }
    }

    auto stage = [&](int buf, int kt) {
#pragma unroll
        for (int i = 0; i < 2; ++i) {
            int c = wid * 128 + i * 64 + lane;
            int row = c >> 3;
            int gch = (c & 7) ^ ((row >> 1) & 7);
            const ushort_t* gk = Kg + ((size_t)(b * Tdim + kt * KVB + row)) * Cdim + h * 64 + gch * 8;
            __builtin_amdgcn_global_load_lds(
                (const __attribute__((address_space(1))) unsigned int*)gk,
                (__attribute__((address_space(3))) unsigned int*)(&KVs[buf][0][0] + (wid * 128 + i * 64) * 8),
                16, 0, 0);
            const ushort_t* gv = Vtg + ((size_t)(bh * 64 + row)) * Tdim + kt * KVB + gch * 8;
            __builtin_amdgcn_global_load_lds(
                (const __attribute__((address_space(1))) unsigned int*)gv,
                (__attribute__((address_space(3))) unsigned int*)(&KVs[buf][1][0] + (wid * 128 + i * 64) * 8),
                16, 0, 0);
        }
    };

    stage(0, 0);
    __syncthreads();

    for (int kt = 0; kt < Tdim / KVB; ++kt) {
        int buf = kt & 1;
        if (kt < Tdim / KVB - 1) stage(buf ^ 1, kt + 1);
        const ushort_t* Ks = &KVs[buf][0][0];
        const ushort_t* Vs = &KVs[buf][1][0];

        // S = Q K^T  (C-frag: row = g*4+q (query), col = tx (key))
        f32x4 sa[2][4];
#pragma unroll
        for (int mi = 0; mi < 2; ++mi)
#pragma unroll
            for (int nf = 0; nf < 4; ++nf) sa[mi][nf] = z;
#pragma unroll
        for (int s = 0; s < 2; ++s)
#pragma unroll
            for (int nf = 0; nf < 4; ++nf) {
                int row = nf * 16 + tx;
                int ch = (g + s * 4) ^ ((row >> 1) & 7);
                bf16x8 kf = *(const bf16x8*)(Ks + row * 64 + ch * 8);
#pragma unroll
                for (int mi = 0; mi < 2; ++mi)
                    sa[mi][nf] = __builtin_amdgcn_mfma_f32_16x16x32_bf16(qf[mi][s], kf, sa[mi][nf], 0, 0, 0);
            }

        // online softmax + P->bf16 LDS
#pragma unroll
        for (int mi = 0; mi < 2; ++mi) {
#pragma unroll
            for (int q = 0; q < 4; ++q) {
                float mx = fmaxf(fmaxf(sa[mi][0][q], sa[mi][1][q]),
                                 fmaxf(sa[mi][2][q], sa[mi][3][q])) * SCALE;
                mx = rmax16(mx);
                float mold = m_run[mi][q];
                float mnew = fmaxf(mold, mx);
                float corr = __expf(mold - mnew);
                m_run[mi][q] = mnew;
                float psum = 0.f;
#pragma unroll
                for (int nf = 0; nf < 4; ++nf) {
                    float p = __expf(fmaf(sa[mi][nf][q], SCALE, -mnew));
                    Ps[wid][(mi * 16 + g * 4 + q) * 68 + nf * 16 + tx] = f2bf(p);
                    psum += p;
                }
                psum = rsum16(psum);
                l_run[mi][q] = l_run[mi][q] * corr + psum;
#pragma unroll
                for (int df = 0; df < 4; ++df) accO[mi][df][q] *= corr;
            }
        }

        // O += P @ V   (A = P from Ps, B = Vt rows)
#pragma unroll
        for (int s2 = 0; s2 < 2; ++s2) {
            U8 pa[2];
#pragma unroll
            for (int mi = 0; mi < 2; ++mi) {
                const ushort_t* pp = &Ps[wid][(mi * 16 + tx) * 68 + s2 * 32 + g * 8];
                pa[mi].u4[0] = *(const ushort4*)pp;
                pa[mi].u4[1] = *(const ushort4*)(pp + 4);
            }
#pragma unroll
            for (int df = 0; df < 4; ++df) {
                int row = df * 16 + tx;
                int ch = (g + s2 * 4) ^ ((row >> 1) & 7);
                bf16x8 vf = *(const bf16x8*)(Vs + row * 64 + ch * 8);
#pragma unroll
                for (int mi = 0; mi < 2; ++mi)
                    accO[mi][df] = __builtin_amdgcn_mfma_f32_16x16x32_bf16(pa[mi].v, vf, accO[mi][df], 0, 0, 0);
            }
        }
        __syncthreads();
    }

    // epilogue: O /= l, write bf16
#pragma unroll
    for (int mi = 0; mi < 2; ++mi)
#pragma unroll
        for (int q = 0; q < 4; ++q) {
            float inv = 1.0f / l_run[mi][q];
            int row = qt * 128 + wid * 32 + mi * 16 + g * 4 + q;
#pragma unroll
            for (int df = 0; df < 4; ++df)
                MO[((size_t)(b * Tdim + row)) * Cdim + h * 64 + df * 16 + tx] =
                    f2bf(accO[mi][df][q] * inv);
        }
}

// ---------------------------------------------------------------------------
extern "C" void kernel_launch(void* const* d_in, const int* in_sizes, int n_in,
                              void* d_out, int out_size, void* d_ws, size_t ws_size,
                              hipStream_t stream) {
    const float* x   = (const float*)d_in[0];
    const float* Wq  = (const float*)d_in[1];
    const float* bq  = (const float*)d_in[2];
    const float* Wk  = (const float*)d_in[3];
    const float* bk  = (const float*)d_in[4];
    const float* Wv  = (const float*)d_in[5];
    const float* bv  = (const float*)d_in[6];
    const float* Wo  = (const float*)d_in[7];
    const float* bo  = (const float*)d_in[8];
    const float* Wr1 = (const float*)d_in[9];
    const float* br1 = (const float*)d_in[10];
    const float* Wr2 = (const float*)d_in[11];
    const float* br2 = (const float*)d_in[12];
    float* out = (float*)d_out;
    float* ws = (float*)d_ws;

    const size_t MF = 1024 * 1024;  // 1M floats
    ushort_t* Qb  = (ushort_t*)ws;                    // 2MF
    ushort_t* Kb  = (ushort_t*)(ws + 2 * MF);         // 2MF
    ushort_t* Vb  = (ushort_t*)(ws + 4 * MF);         // 2MF
    float*    R1b = ws + 6 * MF;                      // 4MF f32 (dead after routing)
    ushort_t* Vtg = (ushort_t*)(ws + 6 * MF);         // aliases R1b lower half
    ushort_t* MOb = (ushort_t*)(ws + 8 * MF);         // aliases R1b upper half
    ushort_t* xb  = (ushort_t*)(ws + 10 * MF);        // 2MF
    ushort_t* Wqt  = (ushort_t*)(ws + 12 * MF);       // 0.5MF each
    ushort_t* Wkt  = (ushort_t*)(ws + 12 * MF + 512 * 1024);
    ushort_t* Wvt  = (ushort_t*)(ws + 13 * MF);
    ushort_t* Wr1t = (ushort_t*)(ws + 13 * MF + 512 * 1024);
    ushort_t* Wot  = (ushort_t*)(ws + 14 * MF);
    float* routing = ws + 14 * MF + 512 * 1024;       // 12288 f
    float* mvec = routing + 12288;                    // 2048 f
    float* tmp2 = mvec + 2048;                        // 3072 f
    float* cvec = tmp2 + 3072;                        // 3072 f

    // --- constants path (tiny, fp32, parallelized) ---
    hipMemsetAsync(mvec, 0, 2048 * sizeof(float), stream);
    colmean_kernel<<<dim3(Bdim, Cdim / 256, 32), 256, 0, stream>>>(x, mvec);
    biasinit_kernel<<<Cdim / 256, 256, 0, stream>>>(bv, tmp2, 3);  // row2 = bv (L3 value vec)
    gemv3_part_kernel<<<dim3(Cdim / 256, 2, 8), 256, 0, stream>>>(mvec, Wv, tmp2);
    biasinit_kernel<<<Cdim / 256, 256, 0, stream>>>(bo, cvec, 3);
    gemv3_part_kernel<<<dim3(Cdim / 256, 3, 8), 256, 0, stream>>>(tmp2, Wo, cvec);

    // --- casts / transposes ---
    cast_bf16_kernel<<<4096, 256, 0, stream>>>(x, xb);
    dim3 tg(16, 16);
    transpose_cast_kernel<<<tg, 256, 0, stream>>>(Wq, Wqt);
    transpose_cast_kernel<<<tg, 256, 0, stream>>>(Wk, Wkt);
    transpose_cast_kernel<<<tg, 256, 0, stream>>>(Wv, Wvt);
    transpose_cast_kernel<<<tg, 256, 0, stream>>>(Wr1, Wr1t);
    transpose_cast_kernel<<<tg, 256, 0, stream>>>(Wo, Wot);

    // --- projections (bf16 MFMA) ---
    dim3 gg(Cdim / 128, M_TOT / 64);  // (8, 64) = 512 blocks
    gemm_bf16<0><<<gg, 256, 0, stream>>>(xb, Wqt, bq, Qb, nullptr, nullptr);
    gemm_bf16<0><<<gg, 256, 0, stream>>>(xb, Wkt, bk, Kb, nullptr, nullptr);
    gemm_bf16<0><<<gg, 256, 0, stream>>>(xb, Wvt, bv, Vb, nullptr, nullptr);
    gemm_bf16<1><<<gg, 256, 0, stream>>>(xb, Wr1t, br1, R1b, nullptr, nullptr);

    // --- routing gate (consumes R1b; then its space becomes Vtg/MOb) ---
    routing_kernel<<<M_TOT / 4, 256, 0, stream>>>(R1b, Wr2, br2, routing);

    // --- V per-head transpose for PV MFMA ---
    transpose_v_kernel<<<dim3(Bdim * Hdim, Tdim / 64), 256, 0, stream>>>(Vb, Vtg);

    // --- MFMA flash attention (level 1) ---
    flash_mfma<<<dim3(Bdim * Hdim, Tdim / 128), 256, 0, stream>>>(Qb, Kb, Vtg, MOb);

    // --- output projection + routing combine ---
    gemm_bf16<2><<<gg, 256, 0, stream>>>(MOb, Wot, bo, (void*)out, routing, cvec);
}

// Round 6
// 318.940 us; speedup vs baseline: 5.1445x; 1.0223x over previous
//
#include <hip/hip_runtime.h>
#include <hip/hip_bf16.h>
#include <math.h>

#define Bdim 2
#define Tdim 2048
#define Cdim 1024
#define Hdim 16
#define SCALE 0.125f
#define M_TOT (Bdim * Tdim)  // 4096
#define Kdim Cdim
#define KVB 64
#define THR 5.5f

typedef __attribute__((ext_vector_type(8))) short bf16x8;
typedef __attribute__((ext_vector_type(4))) float f32x4;
typedef unsigned short ushort_t;

union U8 { bf16x8 v; ushort4 u4[2]; };

__device__ __forceinline__ unsigned short f2bf(float f) {
    union { float f; unsigned u; } v; v.f = f;
    unsigned r = (v.u + 0x7FFFu + ((v.u >> 16) & 1u)) >> 16;
    return (unsigned short)r;
}

// DPP 16-lane reductions (VALU pipe, no LDS traffic).
template <int CTRL>
__device__ __forceinline__ float dppf(float v) {
    int r = __builtin_amdgcn_update_dpp(0, __builtin_bit_cast(int, v), CTRL, 0xF, 0xF, false);
    return __builtin_bit_cast(float, r);
}
__device__ __forceinline__ float rmax16(float v) {
    v = fmaxf(v, dppf<0xB1>(v));   // quad_perm xor1
    v = fmaxf(v, dppf<0x4E>(v));   // quad_perm xor2
    v = fmaxf(v, dppf<0x124>(v));  // row_ror:4
    v = fmaxf(v, dppf<0x128>(v));  // row_ror:8
    return v;
}
__device__ __forceinline__ float rsum16(float v) {
    v += dppf<0xB1>(v);
    v += dppf<0x4E>(v);
    v += dppf<0x124>(v);
    v += dppf<0x128>(v);
    return v;
}

// ---------------------------------------------------------------------------
// Column mean over T: m[b][c] += partial.  grid (B, C/256, 32)
// ---------------------------------------------------------------------------
__global__ void colmean_kernel(const float* __restrict__ x, float* __restrict__ m) {
    int b = blockIdx.x;
    int c = blockIdx.y * 256 + threadIdx.x;
    int t0 = blockIdx.z * 64;
    float s = 0.f;
    for (int t = t0; t < t0 + 64; ++t)
        s += x[((size_t)b * Tdim + t) * Cdim + c];
    atomicAdd(&m[b * Cdim + c], s * (1.0f / Tdim));
}

// out rows 0..R-1 = bias broadcast. grid (C/256)
__global__ void biasinit_kernel(const float* __restrict__ bias, float* __restrict__ out, int R) {
    int c = blockIdx.x * 256 + threadIdx.x;
    for (int r = 0; r < R; ++r) out[(size_t)r * Cdim + c] = bias[c];
}

// out[r][c] += sum over K-slice of rows[r][k]*W[k][c].  grid (C/256, R, 8)
__global__ void gemv3_part_kernel(const float* __restrict__ rows, const float* __restrict__ W,
                                  float* __restrict__ out) {
    int c = blockIdx.x * 256 + threadIdx.x;
    int r = blockIdx.y;
    int k0 = blockIdx.z * 128;
    const float* rp = rows + (size_t)r * Cdim;
    float s = 0.f;
    for (int k = k0; k < k0 + 128; ++k)
        s += rp[k] * W[(size_t)k * Cdim + c];
    atomicAdd(&out[(size_t)r * Cdim + c], s);
}

// ---------------------------------------------------------------------------
// fp32 -> bf16 cast, 4 elems/thread
// ---------------------------------------------------------------------------
__global__ void cast_bf16_kernel(const float* __restrict__ in, ushort_t* __restrict__ out) {
    int i = blockIdx.x * 256 + threadIdx.x;
    float4 v = ((const float4*)in)[i];
    ushort4 o;
    o.x = f2bf(v.x); o.y = f2bf(v.y); o.z = f2bf(v.z); o.w = f2bf(v.w);
    ((ushort4*)out)[i] = o;
}

// ---------------------------------------------------------------------------
// 5 weights [K][N] fp32 -> Wall[w][N][K] bf16.  grid (N/64, K/64, 5)
// ---------------------------------------------------------------------------
__global__ __launch_bounds__(256) void transpose_cast5_kernel(
    const float* __restrict__ W0, const float* __restrict__ W1,
    const float* __restrict__ W2, const float* __restrict__ W3,
    const float* __restrict__ W4, ushort_t* __restrict__ Wall) {
    __shared__ float L[64][65];
    int z = blockIdx.z;
    const float* W = z == 0 ? W0 : z == 1 ? W1 : z == 2 ? W2 : z == 3 ? W3 : W4;
    ushort_t* Wt = Wall + (size_t)z * 1024 * 1024;
    int n0 = blockIdx.x * 64, k0 = blockIdx.y * 64;
    int t = threadIdx.x;
    int c4 = (t & 15) * 4, rr = t >> 4;
#pragma unroll
    for (int i = 0; i < 4; ++i) {
        int k = rr + i * 16;
        float4 v = *(const float4*)(W + (size_t)(k0 + k) * Cdim + n0 + c4);
        L[k][c4 + 0] = v.x; L[k][c4 + 1] = v.y; L[k][c4 + 2] = v.z; L[k][c4 + 3] = v.w;
    }
    __syncthreads();
#pragma unroll
    for (int i = 0; i < 4; ++i) {
        int n = rr + i * 16;
        ushort4 o;
        o.x = f2bf(L[c4 + 0][n]); o.y = f2bf(L[c4 + 1][n]);
        o.z = f2bf(L[c4 + 2][n]); o.w = f2bf(L[c4 + 3][n]);
        *(ushort4*)(Wt + (size_t)(n0 + n) * Kdim + k0 + c4) = o;
    }
}

// ---------------------------------------------------------------------------
// Vb [B*T][C] bf16 -> Vt [(b*H+h)*64 + d][T] bf16 (per-head transpose).
// grid (B*H, T/64)
// ---------------------------------------------------------------------------
__global__ __launch_bounds__(256) void transpose_v_kernel(const ushort_t* __restrict__ Vb,
                                                          ushort_t* __restrict__ Vt) {
    __shared__ ushort_t L[64][72];
    int bh = blockIdx.x, tt = blockIdx.y;
    int b = bh >> 4, h = bh & 15;
    int t = threadIdx.x;
    int tx = t & 15, ty = t >> 4;
#pragma unroll
    for (int it = 0; it < 4; ++it) {
        int tok = ty + it * 16;
        ushort4 v = *(const ushort4*)(Vb + ((size_t)(b * Tdim + tt * 64 + tok)) * Cdim + h * 64 + tx * 4);
        *(ushort4*)&L[tok][tx * 4] = v;
    }
    __syncthreads();
#pragma unroll
    for (int it = 0; it < 4; ++it) {
        int d = ty + it * 16;
        ushort4 o;
        o.x = L[tx * 4 + 0][d]; o.y = L[tx * 4 + 1][d];
        o.z = L[tx * 4 + 2][d]; o.w = L[tx * 4 + 3][d];
        *(ushort4*)(Vt + ((size_t)(bh * 64 + d)) * Tdim + tt * 64 + tx * 4) = o;
    }
}

// ---------------------------------------------------------------------------
// 128x128-tile bf16 MFMA GEMM, BK=64, 8 waves (2m x 4n), each wave 64x32.
// Same proven staging (global_load_lds 16B + chunk-XOR swizzle both sides).
// MODE 3: fused QKVR epilogue steered by n0>>10 (Q/K/V bf16, R1 tanh f32)
// MODE 2: routing combine -> f32 out
// ---------------------------------------------------------------------------
__device__ __forceinline__ void stage128(const ushort_t* __restrict__ A,
                                         const ushort_t* __restrict__ Bt,
                                         ushort_t* ldsbuf, int m0, int n0, int kel,
                                         int wid, int lane) {
#pragma unroll
    for (int i = 0; i < 2; ++i) {
        int c = wid * 128 + i * 64 + lane;         // 0..1023
        int row = c >> 3;                           // 0..127
        int gch = (c & 7) ^ ((c >> 4) & 7);
        const ushort_t* ga = A + (size_t)(m0 + row) * Kdim + kel + gch * 8;
        __builtin_amdgcn_global_load_lds(
            (const __attribute__((address_space(1))) unsigned int*)ga,
            (__attribute__((address_space(3))) unsigned int*)(ldsbuf + (wid * 128 + i * 64) * 8),
            16, 0, 0);
        const ushort_t* gb = Bt + (size_t)(n0 + row) * Kdim + kel + gch * 8;
        __builtin_amdgcn_global_load_lds(
            (const __attribute__((address_space(1))) unsigned int*)gb,
            (__attribute__((address_space(3))) unsigned int*)(ldsbuf + 8192 + (wid * 128 + i * 64) * 8),
            16, 0, 0);
    }
}

template <int MODE>
__global__ __launch_bounds__(512) void gemm128(
    const ushort_t* __restrict__ A, const ushort_t* __restrict__ Bt,
    const float* __restrict__ b0, const float* __restrict__ b1,
    const float* __restrict__ b2, const float* __restrict__ b3,
    ushort_t* __restrict__ oQ, ushort_t* __restrict__ oK, ushort_t* __restrict__ oV,
    float* __restrict__ oF, const float* __restrict__ routing, const float* __restrict__ cvec) {
    __shared__ ushort_t lds[2 * 16384];  // per buf: A 128x64 (8192) + B 128x64 (8192)

    int tid = threadIdx.x, lane = tid & 63, wid = tid >> 6;
    int tx = lane & 15, g = lane >> 4;
    int wm = wid >> 2, wn = wid & 3;
    int m0 = blockIdx.y * 128, n0 = blockIdx.x * 128;

    f32x4 acc[4][2];
    f32x4 z = {0.f, 0.f, 0.f, 0.f};
#pragma unroll
    for (int mi = 0; mi < 4; ++mi)
#pragma unroll
        for (int ni = 0; ni < 2; ++ni) acc[mi][ni] = z;

    stage128(A, Bt, lds, m0, n0, 0, wid, lane);
    __syncthreads();

    int cur = 0;
    for (int t = 0; t < 16; ++t) {
        if (t < 15) stage128(A, Bt, lds + (cur ^ 1) * 16384, m0, n0, (t + 1) * 64, wid, lane);
        const ushort_t* Ab = lds + cur * 16384;
        const ushort_t* Bb = Ab + 8192;
#pragma unroll
        for (int s = 0; s < 2; ++s) {
            int kc = g + s * 4;
            bf16x8 af[4], bfr[2];
#pragma unroll
            for (int mi = 0; mi < 4; ++mi) {
                int row = wm * 64 + mi * 16 + tx;
                int ch = kc ^ ((row >> 1) & 7);
                af[mi] = *(const bf16x8*)(Ab + row * 64 + ch * 8);
            }
#pragma unroll
            for (int ni = 0; ni < 2; ++ni) {
                int row = wn * 32 + ni * 16 + tx;
                int ch = kc ^ ((row >> 1) & 7);
                bfr[ni] = *(const bf16x8*)(Bb + row * 64 + ch * 8);
            }
#pragma unroll
            for (int mi = 0; mi < 4; ++mi)
#pragma unroll
                for (int ni = 0; ni < 2; ++ni)
                    acc[mi][ni] = __builtin_amdgcn_mfma_f32_16x16x32_bf16(
                        af[mi], bfr[ni], acc[mi][ni], 0, 0, 0);
        }
        __syncthreads();
        cur ^= 1;
    }

    if constexpr (MODE == 3) {
        int w = n0 >> 10;  // which projection (uniform per block)
        const float* bias = w == 0 ? b0 : w == 1 ? b1 : w == 2 ? b2 : b3;
        ushort_t* obf = w == 0 ? oQ : w == 1 ? oK : oV;
        int nloc = n0 & 1023;
#pragma unroll
        for (int mi = 0; mi < 4; ++mi)
#pragma unroll
            for (int ni = 0; ni < 2; ++ni) {
                int col = nloc + wn * 32 + ni * 16 + tx;
                float bs = bias[col];
#pragma unroll
                for (int q = 0; q < 4; ++q) {
                    int row = m0 + wm * 64 + mi * 16 + g * 4 + q;
                    float v = acc[mi][ni][q] + bs;
                    if (w == 3)
                        oF[(size_t)row * Cdim + col] = tanhf(v);
                    else
                        obf[(size_t)row * Cdim + col] = f2bf(v);
                }
            }
    } else {
#pragma unroll
        for (int mi = 0; mi < 4; ++mi)
#pragma unroll
            for (int ni = 0; ni < 2; ++ni) {
                int col = n0 + wn * 32 + ni * 16 + tx;
                float bs = b0[col];
#pragma unroll
                for (int q = 0; q < 4; ++q) {
                    int row = m0 + wm * 64 + mi * 16 + g * 4 + q;
                    float v = acc[mi][ni][q] + bs;
                    int b = row >> 11;
                    float r0 = routing[row * 3 + 0];
                    float r1 = routing[row * 3 + 1];
                    float r2 = routing[row * 3 + 2];
                    oF[(size_t)row * Cdim + col] =
                        r0 * v + r1 * cvec[b * Cdim + col] + r2 * cvec[2 * Cdim + col];
                }
            }
    }
}

// ---------------------------------------------------------------------------
// Routing: logits = R1 @ Wr2 + br2; softmax over 3. One wave per row.
// ---------------------------------------------------------------------------
__global__ __launch_bounds__(256) void routing_kernel(
    const float* __restrict__ R1, const float* __restrict__ Wr2,
    const float* __restrict__ br2, float* __restrict__ routing) {
    int wid = threadIdx.x >> 6, lane = threadIdx.x & 63;
    int row = blockIdx.x * 4 + wid;
    const float* rp = R1 + (size_t)row * Cdim;
    float a0 = 0.f, a1 = 0.f, a2 = 0.f;
    for (int k = lane; k < Cdim; k += 64) {
        float xv = rp[k];
        a0 += xv * Wr2[k * 3 + 0];
        a1 += xv * Wr2[k * 3 + 1];
        a2 += xv * Wr2[k * 3 + 2];
    }
#pragma unroll
    for (int off = 32; off; off >>= 1) {
        a0 += __shfl_xor(a0, off);
        a1 += __shfl_xor(a1, off);
        a2 += __shfl_xor(a2, off);
    }
    if (lane == 0) {
        a0 += br2[0]; a1 += br2[1]; a2 += br2[2];
        float mx = fmaxf(a0, fmaxf(a1, a2));
        float e0 = __expf(a0 - mx), e1 = __expf(a1 - mx), e2 = __expf(a2 - mx);
        float inv = 1.0f / (e0 + e1 + e2);
        routing[row * 3 + 0] = e0 * inv;
        routing[row * 3 + 1] = e1 * inv;
        routing[row * 3 + 2] = e2 * inv;
    }
}

// ---------------------------------------------------------------------------
// MFMA flash attention. grid (B*H, T/64), block 256 (4 waves x 16 q-rows).
// Defer-max (THR): skip corr+rescale when no row grows past m+THR.
// ---------------------------------------------------------------------------
__global__ __launch_bounds__(256) void flash_mfma(
    const ushort_t* __restrict__ Qg, const ushort_t* __restrict__ Kg,
    const ushort_t* __restrict__ Vtg, ushort_t* __restrict__ MO) {
    __shared__ ushort_t KVs[2][2][64 * 64];  // [buf][K=0 / Vt=1]
    __shared__ ushort_t Ps[4][16 * 68];

    int tid = threadIdx.x, lane = tid & 63, wid = tid >> 6;
    int tx = lane & 15, g = lane >> 4;
    int bh = blockIdx.x, b = bh >> 4, h = bh & 15;
    int qt = blockIdx.y;

    // Q fragments in registers: A-frag lane: m = tx, k = g*8 + s*32
    bf16x8 qf[2];
#pragma unroll
    for (int s = 0; s < 2; ++s) {
        int row = qt * 64 + wid * 16 + tx;
        qf[s] = *(const bf16x8*)(Qg + ((size_t)(b * Tdim + row)) * Cdim + h * 64 + s * 32 + g * 8);
    }

    f32x4 accO[4];
    f32x4 z = {0.f, 0.f, 0.f, 0.f};
    float m_run[4], l_run[4];
#pragma unroll
    for (int df = 0; df < 4; ++df) accO[df] = z;
#pragma unroll
    for (int q = 0; q < 4; ++q) { m_run[q] = -3e38f; l_run[q] = 0.f; }

    auto stage = [&](int buf, int kt) {
#pragma unroll
        for (int i = 0; i < 2; ++i) {
            int c = wid * 128 + i * 64 + lane;
            int row = c >> 3;
            int gch = (c & 7) ^ ((row >> 1) & 7);
            const ushort_t* gk = Kg + ((size_t)(b * Tdim + kt * KVB + row)) * Cdim + h * 64 + gch * 8;
            __builtin_amdgcn_global_load_lds(
                (const __attribute__((address_space(1))) unsigned int*)gk,
                (__attribute__((address_space(3))) unsigned int*)(&KVs[buf][0][0] + (wid * 128 + i * 64) * 8),
                16, 0, 0);
            const ushort_t* gv = Vtg + ((size_t)(bh * 64 + row)) * Tdim + kt * KVB + gch * 8;
            __builtin_amdgcn_global_load_lds(
                (const __attribute__((address_space(1))) unsigned int*)gv,
                (__attribute__((address_space(3))) unsigned int*)(&KVs[buf][1][0] + (wid * 128 + i * 64) * 8),
                16, 0, 0);
        }
    };

    stage(0, 0);
    __syncthreads();

    for (int kt = 0; kt < Tdim / KVB; ++kt) {
        int buf = kt & 1;
        if (kt < Tdim / KVB - 1) stage(buf ^ 1, kt + 1);
        const ushort_t* Ks = &KVs[buf][0][0];
        const ushort_t* Vs = &KVs[buf][1][0];

        // S = Q K^T  (C-frag: row = g*4+q (query), col = tx (key), nf = key-frag)
        f32x4 sa[4];
#pragma unroll
        for (int nf = 0; nf < 4; ++nf) sa[nf] = z;
#pragma unroll
        for (int s = 0; s < 2; ++s)
#pragma unroll
            for (int nf = 0; nf < 4; ++nf) {
                int row = nf * 16 + tx;
                int ch = (g + s * 4) ^ ((row >> 1) & 7);
                bf16x8 kf = *(const bf16x8*)(Ks + row * 64 + ch * 8);
                sa[nf] = __builtin_amdgcn_mfma_f32_16x16x32_bf16(qf[s], kf, sa[nf], 0, 0, 0);
            }

        // row maxima (scaled), defer-max vote
        float pmax[4];
        int need = 0;
#pragma unroll
        for (int q = 0; q < 4; ++q) {
            float mx = fmaxf(fmaxf(sa[0][q], sa[1][q]), fmaxf(sa[2][q], sa[3][q]));
            pmax[q] = rmax16(mx) * SCALE;
            need |= (pmax[q] > m_run[q] + THR);
        }
        if (__any(need)) {
#pragma unroll
            for (int q = 0; q < 4; ++q) {
                float mnew = fmaxf(m_run[q], pmax[q]);
                float corr = __expf(m_run[q] - mnew);
                l_run[q] *= corr;
#pragma unroll
                for (int df = 0; df < 4; ++df) accO[df][q] *= corr;
                m_run[q] = mnew;
            }
        }

        // P = exp(S*SCALE - m) -> bf16 LDS; accumulate l
#pragma unroll
        for (int q = 0; q < 4; ++q) {
            float psum = 0.f;
#pragma unroll
            for (int nf = 0; nf < 4; ++nf) {
                float p = __expf(fmaf(sa[nf][q], SCALE, -m_run[q]));
                Ps[wid][(g * 4 + q) * 68 + nf * 16 + tx] = f2bf(p);
                psum += p;
            }
            l_run[q] += rsum16(psum);
        }

        // O += P @ V   (A = P from Ps, B = Vt rows)
#pragma unroll
        for (int s2 = 0; s2 < 2; ++s2) {
            U8 pa;
            const ushort_t* pp = &Ps[wid][tx * 68 + s2 * 32 + g * 8];
            pa.u4[0] = *(const ushort4*)pp;
            pa.u4[1] = *(const ushort4*)(pp + 4);
#pragma unroll
            for (int df = 0; df < 4; ++df) {
                int row = df * 16 + tx;
                int ch = (g + s2 * 4) ^ ((row >> 1) & 7);
                bf16x8 vf = *(const bf16x8*)(Vs + row * 64 + ch * 8);
                accO[df] = __builtin_amdgcn_mfma_f32_16x16x32_bf16(pa.v, vf, accO[df], 0, 0, 0);
            }
        }
        __syncthreads();
    }

    // epilogue: O /= l, write bf16
#pragma unroll
    for (int q = 0; q < 4; ++q) {
        float inv = 1.0f / l_run[q];
        int row = qt * 64 + wid * 16 + g * 4 + q;
#pragma unroll
        for (int df = 0; df < 4; ++df)
            MO[((size_t)(b * Tdim + row)) * Cdim + h * 64 + df * 16 + tx] =
                f2bf(accO[df][q] * inv);
    }
}

// ---------------------------------------------------------------------------
extern "C" void kernel_launch(void* const* d_in, const int* in_sizes, int n_in,
                              void* d_out, int out_size, void* d_ws, size_t ws_size,
                              hipStream_t stream) {
    const float* x   = (const float*)d_in[0];
    const float* Wq  = (const float*)d_in[1];
    const float* bq  = (const float*)d_in[2];
    const float* Wk  = (const float*)d_in[3];
    const float* bk  = (const float*)d_in[4];
    const float* Wv  = (const float*)d_in[5];
    const float* bv  = (const float*)d_in[6];
    const float* Wo  = (const float*)d_in[7];
    const float* bo  = (const float*)d_in[8];
    const float* Wr1 = (const float*)d_in[9];
    const float* br1 = (const float*)d_in[10];
    const float* Wr2 = (const float*)d_in[11];
    const float* br2 = (const float*)d_in[12];
    float* out = (float*)d_out;
    float* ws = (float*)d_ws;

    const size_t MF = 1024 * 1024;  // 1M floats
    ushort_t* Qb   = (ushort_t*)ws;                   // 2MF
    ushort_t* Kb   = (ushort_t*)(ws + 2 * MF);        // 2MF
    ushort_t* Vb   = (ushort_t*)(ws + 4 * MF);        // 2MF
    float*    R1b  = ws + 6 * MF;                     // 4MF f32 (dead after routing)
    ushort_t* Vtg  = (ushort_t*)(ws + 6 * MF);        // aliases R1b lower half
    ushort_t* MOb  = (ushort_t*)(ws + 8 * MF);        // aliases R1b upper half
    ushort_t* xb   = (ushort_t*)(ws + 10 * MF);       // 2MF
    ushort_t* Wall = (ushort_t*)(ws + 12 * MF);       // 5M bf16 = 2.5MF
    float* routing = ws + 14 * MF + 512 * 1024;       // 12288 f
    float* mvec = routing + 12288;                    // 2048 f
    float* tmp2 = mvec + 2048;                        // 3072 f
    float* cvec = tmp2 + 3072;                        // 3072 f

    // --- constants path (tiny, fp32, parallelized) ---
    hipMemsetAsync(mvec, 0, 2048 * sizeof(float), stream);
    colmean_kernel<<<dim3(Bdim, Cdim / 256, 32), 256, 0, stream>>>(x, mvec);
    biasinit_kernel<<<Cdim / 256, 256, 0, stream>>>(bv, tmp2, 3);  // row2 = bv (L3 value vec)
    gemv3_part_kernel<<<dim3(Cdim / 256, 2, 8), 256, 0, stream>>>(mvec, Wv, tmp2);
    biasinit_kernel<<<Cdim / 256, 256, 0, stream>>>(bo, cvec, 3);
    gemv3_part_kernel<<<dim3(Cdim / 256, 3, 8), 256, 0, stream>>>(tmp2, Wo, cvec);

    // --- casts / transposes ---
    cast_bf16_kernel<<<4096, 256, 0, stream>>>(x, xb);
    transpose_cast5_kernel<<<dim3(16, 16, 5), 256, 0, stream>>>(Wq, Wk, Wv, Wr1, Wo, Wall);

    // --- fused Q|K|V|R1 projection (bf16 MFMA, 128x128 tile) ---
    gemm128<3><<<dim3(32, 32), 512, 0, stream>>>(xb, Wall, bq, bk, bv, br1,
                                                 Qb, Kb, Vb, R1b, nullptr, nullptr);

    // --- routing gate (consumes R1b; then its space becomes Vtg/MOb) ---
    routing_kernel<<<M_TOT / 4, 256, 0, stream>>>(R1b, Wr2, br2, routing);

    // --- V per-head transpose for PV MFMA ---
    transpose_v_kernel<<<dim3(Bdim * Hdim, Tdim / 64), 256, 0, stream>>>(Vb, Vtg);

    // --- MFMA flash attention (level 1) ---
    flash_mfma<<<dim3(Bdim * Hdim, Tdim / 64), 256, 0, stream>>>(Qb, Kb, Vtg, MOb);

    // --- output projection + routing combine (Wall slice w=4 is Wo^T) ---
    gemm128<2><<<dim3(8, 32), 512, 0, stream>>>(MOb, Wall + (size_t)4 * 1024 * 1024,
                                                bo, nullptr, nullptr, nullptr,
                                                nullptr, nullptr, nullptr,
                                                out, routing, cvec);
}